// Round 7
// baseline (82.758 us; speedup 1.0000x reference)
//
#include <hip/hip_runtime.h>
#include <cstdint>

// OctantQuery: pcs [B,3,N] f32 -> out [B,N,9,K] int32.
// R0 wave mapping + load structure (proven; R2/R4/R5/R6 probes showed the
// memory side is not the bottleneck). This version removes the per-octant
// SALU/branch pipeline -- the suspected real cost (shared scalar/branch unit,
// ~12 taken branches + ~46 SALU per nonempty chunk) -- and replaces it with
// branchless per-lane placement:
//   sel  = mw & (bx?mx:~mx) & (by?my:~my) & (bz?mz:~mz)   (lane's octant mask)
//   rank = popc(sel & below_lane_mask)
//   base = 7-cndmask select tree over the 8 wave-uniform counters
//   one predicated store per chunk (vs up to 8 divergent store sections)
// Counter updates are 30 straight-line unconditional SALU ops (no branches).
// Self-exclusion is a branchless SALU cselect on mw. Empty-chunk skip branch
// (~70% of chunks) is kept. __launch_bounds__(256,8) pins 8 waves/SIMD.

#define NPTS   2048
#define KSAMP  32
#define RAD2   0.16f

__global__ __launch_bounds__(256, 8) void octant_query_kernel(
    const float* __restrict__ pcs, int* __restrict__ out, int nblocks) {
#pragma clang fp contract(off)
    const int wid  = (int)(threadIdx.x >> 6);
    const int lane = (int)(threadIdx.x & 63);
    const int m    = (int)blockIdx.x;
    if (m >= nblocks) return;

    // L1-locality swizzle (R6, neutral but free): same-CU chain shares a batch
    const int b = m & 3;
    const int i = (m >> 2) * 4 + wid;

    const float* __restrict__ px = pcs + (size_t)b * 3 * NPTS;
    const float* __restrict__ py = px + NPTS;
    const float* __restrict__ pz = py + NPTS;

    const float cx = px[i];
    const float cy = py[i];
    const float cz = pz[i];

    int* __restrict__ obase = out + (size_t)(b * NPTS + i) * 9 * KSAMP;

    const int ichunk = i >> 6;
    const unsigned long long notself = ~(1ULL << (i & 63));
    const unsigned long long below  = (1ULL << lane) - 1ULL;  // bits strictly below my lane

    int cnt0 = 0, cnt1 = 0, cnt2 = 0, cnt3 = 0;
    int cnt4 = 0, cnt5 = 0, cnt6 = 0, cnt7 = 0;

    for (int c = 0; c < NPTS; c += 64) {
        const int j = c + lane;
        const float dx = px[j] - cx;
        const float dy = py[j] - cy;
        const float dz = pz[j] - cz;
        // match numpy rounding: no fp contraction (pragma above), left-assoc
        float d2 = dx * dx;
        d2 = d2 + dy * dy;
        d2 = d2 + dz * dz;

        unsigned long long mw = __ballot(d2 < RAD2);
        // branchless wave-uniform self-exclusion (SALU cselect)
        mw &= ((c >> 6) == ichunk) ? notself : ~0ULL;
        if (mw == 0ULL) continue;                 // wave-uniform skip (~70%)

        const unsigned long long mx = __ballot(dx > 0.f);
        const unsigned long long my = __ballot(dy > 0.f);
        const unsigned long long mz = __ballot(dz > 0.f);

        // ---- per-lane branchless placement (VALU, no scalar branches) ----
        const bool bx = dx > 0.f;
        const bool by = dy > 0.f;
        const bool bz = dz > 0.f;
        const unsigned long long fx = bx ? mx : ~mx;
        const unsigned long long fy = by ? my : ~my;
        const unsigned long long fz = bz ? mz : ~mz;
        const unsigned long long sel = (mw & fx) & (fy & fz); // my octant's mask
        const int rank = (int)__popcll(sel & below);

        // base = cnt[oct] via 7-cndmask tree (counters are wave-uniform)
        const int c01 = bx ? cnt1 : cnt0;
        const int c23 = bx ? cnt3 : cnt2;
        const int c45 = bx ? cnt5 : cnt4;
        const int c67 = bx ? cnt7 : cnt6;
        const int cA  = by ? c23 : c01;
        const int cB  = by ? c67 : c45;
        const int base = bz ? cB : cA;

        const int o = (bx ? 1 : 0) + (by ? 2 : 0) + (bz ? 4 : 0);
        const int r = base + rank;
        const bool mine = (mw >> lane) & 1ULL;    // within & not-self
        if (mine && r < KSAMP) obase[o * KSAMP + r] = j;  // ONE store section

        // ---- wave-uniform counter update: straight-line SALU, no branches --
        const unsigned long long a0 = mw & ~mx, a1 = mw & mx;
        const unsigned long long q0 = a0 & ~my, q1 = a1 & ~my;
        const unsigned long long q2 = a0 &  my, q3 = a1 &  my;
        cnt0 += (int)__popcll(q0 & ~mz);
        cnt1 += (int)__popcll(q1 & ~mz);
        cnt2 += (int)__popcll(q2 & ~mz);
        cnt3 += (int)__popcll(q3 & ~mz);
        cnt4 += (int)__popcll(q0 &  mz);
        cnt5 += (int)__popcll(q1 &  mz);
        cnt6 += (int)__popcll(q2 &  mz);
        cnt7 += (int)__popcll(q3 &  mz);
    }

    // pad remaining slots with center index i (each slot written exactly once)
#define FILL(o, cnt)                                                        \
        {                                                                   \
            const int s = cnt + lane;                                       \
            if (s < KSAMP) obase[(o) * KSAMP + s] = i;                      \
        }
    FILL(0, cnt0) FILL(1, cnt1) FILL(2, cnt2) FILL(3, cnt3)
    FILL(4, cnt4) FILL(5, cnt5) FILL(6, cnt6) FILL(7, cnt7)
#undef FILL
    if (lane < KSAMP) obase[8 * KSAMP + lane] = i;
}

extern "C" void kernel_launch(void* const* d_in, const int* in_sizes, int n_in,
                              void* d_out, int out_size, void* d_ws, size_t ws_size,
                              hipStream_t stream) {
    const float* pcs = (const float*)d_in[0];
    int* out = (int*)d_out;
    const int B = in_sizes[0] / (3 * NPTS);   // 4
    const int nblocks = B * NPTS / 4;         // one wave per center, 4 waves/block
    const int block = 256;
    octant_query_kernel<<<nblocks, block, 0, stream>>>(pcs, out, nblocks);
}

// Round 8
// 78.938 us; speedup vs baseline: 1.0484x; 1.0484x over previous
//
#include <hip/hip_runtime.h>
#include <cstdint>

// OctantQuery: pcs [B,3,N] f32 -> out [B,N,9,K] int32.
// R0 control flow exactly (proven best over 6 probes: one wave per center,
// 64-candidate chunks, ballot -> wave-uniform empty skip -> per-octant
// conditional sections). This version only REMOVES instructions from the
// nonempty path, keeping structure identical:
//  - all 8 octant masks from a shared 14-op SALU and-tree (was 24 ands)
//  - per-lane store predicate via precomputed octant code (o_lane == o,
//    1 v_cmp) instead of a 64-bit mask shift per octant (~4 VALU x 8)
//  - branchless SALU self-exclusion on the ballot (R6, proven safe)
// No launch_bounds min-wave pin (R7 lesson: pinning + register growth =>
// scratch spills in the hot loop). Natural VGPR allocation.

#define NPTS   2048
#define KSAMP  32
#define RAD2   0.16f

__device__ __forceinline__ unsigned rank_below(unsigned long long mask) {
    // number of set bits in `mask` at lane positions strictly below mine
    return __builtin_amdgcn_mbcnt_hi((unsigned)(mask >> 32),
           __builtin_amdgcn_mbcnt_lo((unsigned)(mask & 0xffffffffu), 0u));
}

__global__ __launch_bounds__(256) void octant_query_kernel(
    const float* __restrict__ pcs, int* __restrict__ out, int nblocks) {
#pragma clang fp contract(off)
    const int wid  = (int)(threadIdx.x >> 6);
    const int lane = (int)(threadIdx.x & 63);
    const int m    = (int)blockIdx.x;
    if (m >= nblocks) return;

    // L1-locality swizzle (R6: neutral, free): same-CU chain shares a batch
    const int b = m & 3;
    const int i = (m >> 2) * 4 + wid;

    const float* __restrict__ px = pcs + (size_t)b * 3 * NPTS;
    const float* __restrict__ py = px + NPTS;
    const float* __restrict__ pz = py + NPTS;

    const float cx = px[i];
    const float cy = py[i];
    const float cz = pz[i];

    int* __restrict__ obase = out + (size_t)(b * NPTS + i) * 9 * KSAMP;

    const int ichunk = i >> 6;
    const unsigned long long notself = ~(1ULL << (i & 63));

    int cnt0 = 0, cnt1 = 0, cnt2 = 0, cnt3 = 0;
    int cnt4 = 0, cnt5 = 0, cnt6 = 0, cnt7 = 0;

    for (int c = 0; c < NPTS; c += 64) {
        const int j = c + lane;
        const float dx = px[j] - cx;
        const float dy = py[j] - cy;
        const float dz = pz[j] - cz;
        // match numpy rounding: no fp contraction (pragma above), left-assoc
        float d2 = dx * dx;
        d2 = d2 + dy * dy;
        d2 = d2 + dz * dz;

        unsigned long long mw = __ballot(d2 < RAD2);
        // branchless wave-uniform self-exclusion (SALU cselect)
        mw &= ((c >> 6) == ichunk) ? notself : ~0ULL;
        if (mw == 0ULL) continue;                 // wave-uniform skip (~70%)

        const unsigned long long mx = __ballot(dx > 0.f);
        const unsigned long long my = __ballot(dy > 0.f);
        const unsigned long long mz = __ballot(dz > 0.f);

        // per-lane octant code, computed once (3 VALU); store predicate per
        // octant is (within && o_lane==o): 1 v_cmp instead of 64-bit shifts
        const bool within = (mw >> lane) & 1ULL;
        const int o_lane = (dx > 0.f ? 1 : 0) + (dy > 0.f ? 2 : 0)
                         + (dz > 0.f ? 4 : 0);

        // shared SALU and-tree: all 8 octant masks in 14 ops (was 24)
        const unsigned long long a0 = mw & ~mx, a1 = mw & mx;
        const unsigned long long q0 = a0 & ~my, q1 = a1 & ~my;
        const unsigned long long q2 = a0 &  my, q3 = a1 &  my;
        const unsigned long long m0 = q0 & ~mz, m1 = q1 & ~mz;
        const unsigned long long m2 = q2 & ~mz, m3 = q3 & ~mz;
        const unsigned long long m4 = q0 &  mz, m5 = q1 &  mz;
        const unsigned long long m6 = q2 &  mz, m7 = q3 &  mz;

#define DO_OCT(o, mo, cnt)                                                  \
        {                                                                   \
            if (mo) {                             /* uniform skip */        \
                if (within && o_lane == (o)) {                              \
                    const int r = cnt + (int)rank_below(mo);                \
                    if (r < KSAMP) obase[(o) * KSAMP + r] = j;              \
                }                                                           \
                cnt += (int)__popcll(mo);                                   \
            }                                                               \
        }
        DO_OCT(0, m0, cnt0) DO_OCT(1, m1, cnt1)
        DO_OCT(2, m2, cnt2) DO_OCT(3, m3, cnt3)
        DO_OCT(4, m4, cnt4) DO_OCT(5, m5, cnt5)
        DO_OCT(6, m6, cnt6) DO_OCT(7, m7, cnt7)
#undef DO_OCT
    }

    // pad remaining slots with center index i (each slot written exactly once)
#define FILL(o, cnt)                                                        \
        {                                                                   \
            const int s = cnt + lane;                                       \
            if (s < KSAMP) obase[(o) * KSAMP + s] = i;                      \
        }
    FILL(0, cnt0) FILL(1, cnt1) FILL(2, cnt2) FILL(3, cnt3)
    FILL(4, cnt4) FILL(5, cnt5) FILL(6, cnt6) FILL(7, cnt7)
#undef FILL
    if (lane < KSAMP) obase[8 * KSAMP + lane] = i;
}

extern "C" void kernel_launch(void* const* d_in, const int* in_sizes, int n_in,
                              void* d_out, int out_size, void* d_ws, size_t ws_size,
                              hipStream_t stream) {
    const float* pcs = (const float*)d_in[0];
    int* out = (int*)d_out;
    const int B = in_sizes[0] / (3 * NPTS);   // 4
    const int nblocks = B * NPTS / 4;         // one wave per center, 4 waves/block
    const int block = 256;
    octant_query_kernel<<<nblocks, block, 0, stream>>>(pcs, out, nblocks);
}

// Round 10
// 70.206 us; speedup vs baseline: 1.1788x; 1.1244x over previous
//
#include <hip/hip_runtime.h>
#include <cstdint>

// OctantQuery: pcs [B,3,N] f32 -> out [B,N,9,K] int32.
// One wave (64 lanes) per center point. Lanes scan 64 candidate j's per
// iteration. Sparse-aware: ~0.6% of pairs are within radius, so ~70% of
// 64-candidate chunks are empty -> ballot(within) once and skip the whole
// octant pipeline on a wave-uniform branch. Nonempty chunks build per-octant
// masks in SALU from 4 ballots and skip zero octants.
//
// FINAL (session verdict): this exact structure measured 70.19/70.6/70.31 us
// across three sessions. Six orthogonal probes (LDS staging, load batching,
// 2 centers/wave, L1 batch swizzle, branchless placement, shared-mask-tree
// instruction reduction) each regressed or were neutral -> the kernel-side
// residual (~29 us over the harness's ~41 us poison-fill floor) is not bound
// by memory latency/locality/MLP, occupancy, branch count, or instruction
// count. Restored champion, byte-identical to the verified best.

#define NPTS   2048
#define KSAMP  32
#define RAD2   0.16f

__device__ __forceinline__ unsigned rank_below(unsigned long long mask) {
    // number of set bits in `mask` at lane positions strictly below mine
    return __builtin_amdgcn_mbcnt_hi((unsigned)(mask >> 32),
           __builtin_amdgcn_mbcnt_lo((unsigned)(mask & 0xffffffffu), 0u));
}

__global__ __launch_bounds__(256) void octant_query_kernel(
    const float* __restrict__ pcs, int* __restrict__ out, int nwaves) {
#pragma clang fp contract(off)
    const int wave = (int)((blockIdx.x * blockDim.x + threadIdx.x) >> 6);
    const int lane = (int)(threadIdx.x & 63);
    if (wave >= nwaves) return;
    const int b = wave >> 11;        // N = 2048
    const int i = wave & (NPTS - 1);

    const float* __restrict__ px = pcs + (size_t)b * 3 * NPTS;
    const float* __restrict__ py = px + NPTS;
    const float* __restrict__ pz = py + NPTS;

    const float cx = px[i];
    const float cy = py[i];
    const float cz = pz[i];

    int* __restrict__ obase = out + (size_t)(b * NPTS + i) * 9 * KSAMP;

    int cnt0 = 0, cnt1 = 0, cnt2 = 0, cnt3 = 0;
    int cnt4 = 0, cnt5 = 0, cnt6 = 0, cnt7 = 0;

    for (int c = 0; c < NPTS; c += 64) {
        const int j = c + lane;
        const float dx = px[j] - cx;
        const float dy = py[j] - cy;
        const float dz = pz[j] - cz;
        // match numpy rounding: no fp contraction (pragma above), left-assoc
        float d2 = dx * dx;
        d2 = d2 + dy * dy;
        d2 = d2 + dz * dz;
        const bool within = (d2 < RAD2) && (j != i);
        const unsigned long long mw = __ballot(within);
        if (mw == 0ULL) continue;                 // wave-uniform skip (~70%)

        const unsigned long long mx = __ballot(dx > 0.f);
        const unsigned long long my = __ballot(dy > 0.f);
        const unsigned long long mz = __ballot(dz > 0.f);

#define DO_OCT(o, cnt)                                                      \
        {                                                                   \
            unsigned long long m = mw;                                      \
            m &= ((o) & 1) ? mx : ~mx;                                      \
            m &= ((o) & 2) ? my : ~my;                                      \
            m &= ((o) & 4) ? mz : ~mz;                                      \
            if (m) {                              /* uniform skip */        \
                const bool mine = (m >> lane) & 1ULL;                       \
                if (mine) {                                                 \
                    const int r = cnt + (int)rank_below(m);                 \
                    if (r < KSAMP) obase[(o) * KSAMP + r] = j;              \
                }                                                           \
                cnt += (int)__popcll(m);                                    \
            }                                                               \
        }
        DO_OCT(0, cnt0) DO_OCT(1, cnt1) DO_OCT(2, cnt2) DO_OCT(3, cnt3)
        DO_OCT(4, cnt4) DO_OCT(5, cnt5) DO_OCT(6, cnt6) DO_OCT(7, cnt7)
#undef DO_OCT
    }

    // pad remaining slots with center index i (each slot written exactly once)
#define FILL(o, cnt)                                                        \
        {                                                                   \
            const int s = cnt + lane;                                       \
            if (s < KSAMP) obase[(o) * KSAMP + s] = i;                      \
        }
    FILL(0, cnt0) FILL(1, cnt1) FILL(2, cnt2) FILL(3, cnt3)
    FILL(4, cnt4) FILL(5, cnt5) FILL(6, cnt6) FILL(7, cnt7)
#undef FILL
    if (lane < KSAMP) obase[8 * KSAMP + lane] = i;
}

extern "C" void kernel_launch(void* const* d_in, const int* in_sizes, int n_in,
                              void* d_out, int out_size, void* d_ws, size_t ws_size,
                              hipStream_t stream) {
    const float* pcs = (const float*)d_in[0];
    int* out = (int*)d_out;
    const int B = in_sizes[0] / (3 * NPTS);   // 4
    const int nwaves = B * NPTS;              // one wave per center
    const int block = 256;                    // 4 waves/block
    const int grid = (nwaves * 64 + block - 1) / block;
    octant_query_kernel<<<grid, block, 0, stream>>>(pcs, out, nwaves);
}